// Round 2
// baseline (724.349 us; speedup 1.0000x reference)
//
#include <hip/hip_runtime.h>
#include <math.h>

// Problem constants (DeformConv_68109591380935) — ALL TENSORS FLOAT32
#define BN_    4
#define CHI_   256
#define CHO_   256
#define HH_    96
#define WW_    96
#define HW_    (HH_*WW_)        // 9216
#define KK_    9
#define CK_    (CHI_*KK_)       // 2304
#define NRED_  (BN_*HW_)        // 36864 samples per BN channel
#define BN_EPS_ 1e-5f

// deform_main tiling: 256 oc x 64 px per block (gather done ONCE per pixel)
#define TPX_   64
#define KC_    64               // K-chunk in LDS
// s_w: pitch 64 shorts (128B) + XOR swizzle (row&7)<<4 — bank-conflict-free
// s_cols: pitch 72 shorts (144B, +8 pad) — unchanged known-good

#define CPITCH_ 72

// offset_mfma tiling: 32 oc (27 + 5 zero) x 64 px, KC 96
#define OKC_    96
#define OPITCH_ 104             // 208B rows (known-good class from R4)

typedef short short8 __attribute__((ext_vector_type(8)));
typedef float f32x4  __attribute__((ext_vector_type(4)));
typedef _Float16 half4 __attribute__((ext_vector_type(4)));

// Per-(tap,pixel) gather metadata: 4 clamped corner offsets (pixel index in
// channel image, <9216 so ushort fits) + 4 bilinear weights premultiplied by
// validity and sigmoid(mask). 16B -> one ds_read_b128.
struct __align__(16) Meta {
    unsigned short off0, off1, off2, off3;
    half4 w;
};

// round-to-nearest-even f32 -> bf16 bit pattern
__device__ __forceinline__ unsigned short f2bf(float v) {
    union { float f; unsigned u; } c; c.f = v;
    unsigned lsb = (c.u >> 16) & 1u;
    c.u += 0x7fffu + lsb;
    return (unsigned short)(c.u >> 16);
}

// ---------------------------------------------------------------------------
// Kernel 0: f32 -> bf16 convert (used for w_conv and w_offset)
// ---------------------------------------------------------------------------
__global__ __launch_bounds__(256) void w2b(
    const float* __restrict__ w, unsigned short* __restrict__ wb)
{
    int idx = blockIdx.x * 256 + threadIdx.x;
    wb[idx] = f2bf(w[idx]);
}

// ---------------------------------------------------------------------------
// Kernel 1: offset conv as MFMA GEMM (UNCHANGED from baseline).
//   om[b, 27, HW] = Woff[27,2304] x im2col3x3(x)  + b_offset
// ---------------------------------------------------------------------------
__global__ __launch_bounds__(256) void offset_mfma(
    const float* __restrict__ x, const unsigned short* __restrict__ wob,
    const float* __restrict__ bo, float* __restrict__ om)
{
    __shared__ __align__(16) unsigned short s_w[32 * OPITCH_];     //  6656 B
    __shared__ __align__(16) unsigned short s_cols[TPX_ * OPITCH_];// 13312 B

    const int t = threadIdx.x;
    const int pixtile = blockIdx.x % (HW_ / TPX_);   // 144
    const int b       = blockIdx.x / (HW_ / TPX_);   // 4
    const int p0 = pixtile * TPX_;

    const int lane = t & 63, wave = t >> 6;
    const int quad = lane >> 4, l15 = lane & 15;

    const int i   = t & 63;            // pixel within tile (staging role)
    const int jlb = (t >> 6) * 24;     // k-subrange within chunk
    const int p   = p0 + i;
    const int h   = p / WW_, w = p % WW_;
    const float* xb = x + (size_t)b * CHI_ * HW_;

    f32x4 acc[2];
    acc[0] = (f32x4){0.f,0.f,0.f,0.f};
    acc[1] = (f32x4){0.f,0.f,0.f,0.f};

    for (int kc = 0; kc < CK_ / OKC_; kc++) {        // 24 chunks
        const int j0 = kc * OKC_;
        if (kc) __syncthreads();
        // ---- stage Woff chunk: 32 x 96 (rows >=27 zero), 3 uint2 per thread
#pragma unroll
        for (int n = 0; n < 3; n++) {
            int e = t + n * 256;                     // < 768
            int ocl = e / 24, kq = e % 24;
            uint2 v = make_uint2(0u, 0u);
            if (ocl < 27)
                v = *reinterpret_cast<const uint2*>(wob + (size_t)ocl * CK_ + j0 + kq * 4);
            *reinterpret_cast<uint2*>(&s_w[ocl * OPITCH_ + kq * 4]) = v;
        }
        // ---- stage im2col chunk: 96 k x 64 px, 24 per thread, 3x b128 write
        union { unsigned short s[24]; uint4 q[3]; } pk;
#pragma unroll
        for (int m = 0; m < 24; m++) {
            int jg = j0 + jlb + m;
            int c  = (jg * 7282) >> 16;              // jg/9
            int k  = jg - 9 * c;
            int yy = h + k / 3 - 1, xx = w + k % 3 - 1;
            bool ok = ((unsigned)yy < HH_) & ((unsigned)xx < WW_);
            float v = ok ? xb[(size_t)c * HW_ + yy * WW_ + xx] : 0.f;
            pk.s[m] = f2bf(v);
        }
        {
            uint4* dst = reinterpret_cast<uint4*>(&s_cols[i * OPITCH_ + jlb]);
            dst[0] = pk.q[0]; dst[1] = pk.q[1]; dst[2] = pk.q[2];
        }
        __syncthreads();
        // ---- MFMA: 3 K-steps, A = 2 oc-tiles, B = this wave's pixel quarter
#pragma unroll
        for (int ks = 0; ks < OKC_ / 32; ks++) {
            short8 a0 = *reinterpret_cast<const short8*>(
                &s_w[(l15) * OPITCH_ + ks * 32 + quad * 8]);
            short8 a1 = *reinterpret_cast<const short8*>(
                &s_w[(16 + l15) * OPITCH_ + ks * 32 + quad * 8]);
            short8 b0 = *reinterpret_cast<const short8*>(
                &s_cols[(wave * 16 + l15) * OPITCH_ + ks * 32 + quad * 8]);
            acc[0] = __builtin_amdgcn_mfma_f32_16x16x32_bf16(a0, b0, acc[0], 0, 0, 0);
            acc[1] = __builtin_amdgcn_mfma_f32_16x16x32_bf16(a1, b0, acc[1], 0, 0, 0);
        }
    }

    // epilogue: C/D layout col=lane&15 (pixel), row=quad*4+r (oc)
#pragma unroll
    for (int mt = 0; mt < 2; mt++) {
#pragma unroll
        for (int r = 0; r < 4; r++) {
            int oc = mt * 16 + quad * 4 + r;
            if (oc < 27) {
                int pix = p0 + wave * 16 + l15;
                om[((size_t)b * 27 + oc) * HW_ + pix] = acc[mt][r] + bo[oc];
            }
        }
    }
}

// ---------------------------------------------------------------------------
// Kernel 2: fused deformable gather + bf16 MFMA GEMM
//   Block: 256 oc x 64 px. 4 waves, each 64 oc x 64 px = 4x4 MFMA tiles.
//   R1: per-(k,px) meta precomputed in LDS (offsets+premasked f16 weights);
//       gather inner loop = 1 ds_read_b128 + 4 loads + 4 FMA, batched 8-wide;
//       s_w pitch 64 + XOR swizzle; XCD-aware block swizzle.
// ---------------------------------------------------------------------------
__global__ __launch_bounds__(256, 3) void deform_main(
    const float* __restrict__ x, const float* __restrict__ om,
    const unsigned short* __restrict__ wb, const float* __restrict__ bconv,
    float* __restrict__ outb)
{
    __shared__ __align__(16) unsigned short s_w[CHO_ * 64];         // 32768 B (swizzled)
    __shared__ __align__(16) unsigned short s_cols[TPX_ * CPITCH_]; //  9216 B
    __shared__ Meta s_meta[KK_ * TPX_];                             //  9216 B

    const int t = threadIdx.x;
    // XCD-aware bijective swizzle: 576 blocks = 8 XCDs x 72 contiguous tiles
    const int bid = blockIdx.x;
    const int swz = (bid & 7) * 72 + (bid >> 3);
    const int pixtile = swz % (HW_ / TPX_);          // 144
    const int b       = swz / (HW_ / TPX_);          // 4
    const int p0 = pixtile * TPX_;

    // ---- meta: offsets + premasked weights for 9 taps x 64 pixels ----
    for (int e = t; e < KK_ * TPX_; e += 256) {
        int k = e >> 6, i = e & 63;                  // TPX_ == 64
        int p = p0 + i;
        int h = p / WW_, w = p % WW_;
        const float* omb = om + ((size_t)b * 27) * HW_ + p;
        float dy  = omb[(2 * k) * HW_];
        float dx  = omb[(2 * k + 1) * HW_];
        float msk = 1.f / (1.f + __expf(-omb[(18 + k) * HW_]));
        float py = dy + (float)(h + k / 3 - 1);
        float px = dx + (float)(w + (k % 3) - 1);
        float y0f = floorf(py), x0f = floorf(px);
        float ly = py - y0f, lx = px - x0f;
        int y0 = (int)y0f, x0 = (int)x0f;
        float vy0 = ((unsigned)y0       < HH_) ? 1.f : 0.f;
        float vy1 = ((unsigned)(y0 + 1) < HH_) ? 1.f : 0.f;
        float vx0 = ((unsigned)x0       < WW_) ? 1.f : 0.f;
        float vx1 = ((unsigned)(x0 + 1) < WW_) ? 1.f : 0.f;
        int yc0 = min(max(y0, 0), HH_ - 1), yc1 = min(max(y0 + 1, 0), HH_ - 1);
        int xc0 = min(max(x0, 0), WW_ - 1), xc1 = min(max(x0 + 1, 0), WW_ - 1);
        float wy0 = 1.f - ly, wx0 = 1.f - lx;
        Meta mt;
        mt.off0 = (unsigned short)(yc0 * WW_ + xc0);
        mt.off1 = (unsigned short)(yc0 * WW_ + xc1);
        mt.off2 = (unsigned short)(yc1 * WW_ + xc0);
        mt.off3 = (unsigned short)(yc1 * WW_ + xc1);
        mt.w = (half4){ (_Float16)(wy0 * wx0 * vy0 * vx0 * msk),
                        (_Float16)(wy0 * lx  * vy0 * vx1 * msk),
                        (_Float16)(ly  * wx0 * vy1 * vx0 * msk),
                        (_Float16)(ly  * lx  * vy1 * vx1 * msk) };
        s_meta[e] = mt;
    }

    const int lane = t & 63, wave = t >> 6;
    const int quad = lane >> 4, l15 = lane & 15;
    const int ib   = t & 63;           // pixel (staging role)
    const int jlb  = (t >> 6) << 4;    // 0,16,32,48
    const int wswz = (l15 & 7) << 4;   // s_w read swizzle (uniform per thread)

    f32x4 acc[4][4];
#pragma unroll
    for (int m = 0; m < 4; m++)
#pragma unroll
        for (int n = 0; n < 4; n++)
            acc[m][n] = (f32x4){0.f, 0.f, 0.f, 0.f};

    const float* xb = x + (size_t)b * CHI_ * HW_;
    char* swb = (char*)s_w;

    __syncthreads();   // meta visible

    for (int kc = 0; kc < CK_ / KC_; kc++) {       // 36 chunks
        const int j0 = kc * KC_;
        if (kc) __syncthreads();
        // ---- stage W chunk: 256 oc x 64 k, 8 x uint4 per thread, swizzled
#pragma unroll
        for (int n = 0; n < 8; n++) {
            int e = t + n * 256;                   // < 2048
            int ocl = e >> 3, ko = e & 7;
            uint4 v = *reinterpret_cast<const uint4*>(
                wb + (size_t)ocl * CK_ + j0 + ko * 8);
            int boff = (ocl << 7) + ((ko << 4) ^ ((ocl & 7) << 4));
            *reinterpret_cast<uint4*>(swb + boff) = v;
        }
        // ---- stage cols: 64 k x 64 px gather via precomputed meta,
        //      2 half-batches of 8 (>=32 loads in flight)
        union { unsigned short s[16]; uint4 q[2]; } pk;
#pragma unroll
        for (int hf = 0; hf < 2; hf++) {
            float f0[8], f1[8], f2[8], f3[8];
            half4 wv[8];
#pragma unroll
            for (int m = 0; m < 8; m++) {
                int jg = j0 + jlb + hf * 8 + m;
                int c  = (jg * 7282) >> 16;        // jg/9
                int k  = jg - 9 * c;
                Meta mt = s_meta[k * TPX_ + ib];
                const float* img = xb + (size_t)c * HW_;
                f0[m] = img[mt.off0];
                f1[m] = img[mt.off1];
                f2[m] = img[mt.off2];
                f3[m] = img[mt.off3];
                wv[m] = mt.w;
            }
#pragma unroll
            for (int m = 0; m < 8; m++) {
                float v = f0[m] * (float)wv[m][0] + f1[m] * (float)wv[m][1]
                        + f2[m] * (float)wv[m][2] + f3[m] * (float)wv[m][3];
                pk.s[hf * 8 + m] = f2bf(v);
            }
        }
        {
            uint4* dst = reinterpret_cast<uint4*>(&s_cols[ib * CPITCH_ + jlb]);
            dst[0] = pk.q[0]; dst[1] = pk.q[1];
        }
        __syncthreads();
        // ---- MFMA: 2 K-steps of 32; wave = 64-oc slice, full 64 px ----
#pragma unroll
        for (int ks = 0; ks < KC_ / 32; ks++) {
            short8 afr[4], bfr[4];
#pragma unroll
            for (int m = 0; m < 4; m++) {
                int rbase = wave * 64 + m * 16 + l15;
                int boff  = (rbase << 7) + ((ks * 64 + quad * 16) ^ wswz);
                afr[m] = *reinterpret_cast<const short8*>(swb + boff);
            }
#pragma unroll
            for (int n = 0; n < 4; n++)
                bfr[n] = *reinterpret_cast<const short8*>(
                    &s_cols[(n * 16 + l15) * CPITCH_ + ks * 32 + quad * 8]);
#pragma unroll
            for (int m = 0; m < 4; m++)
#pragma unroll
                for (int n = 0; n < 4; n++)
                    acc[m][n] = __builtin_amdgcn_mfma_f32_16x16x32_bf16(
                        afr[m], bfr[n], acc[m][n], 0, 0, 0);
        }
    }

    // ---- epilogue: C/D layout col=lane&15 (pixel), row=quad*4+r (oc) ----
#pragma unroll
    for (int m = 0; m < 4; m++) {
#pragma unroll
        for (int n = 0; n < 4; n++) {
#pragma unroll
            for (int r = 0; r < 4; r++) {
                int oc  = wave * 64 + m * 16 + quad * 4 + r;
                int pix = p0 + n * 16 + l15;
                outb[((size_t)b * CHO_ + oc) * HW_ + pix] = acc[m][n][r] + bconv[oc];
            }
        }
    }
}

// ---------------------------------------------------------------------------
// Kernel 3: BN statistics (sum, sumsq) per channel, deterministic two-pass
// ---------------------------------------------------------------------------
__global__ __launch_bounds__(256) void bn_stats(
    const float* __restrict__ outb, float* __restrict__ stats)
{
    int o = blockIdx.x, t = threadIdx.x;
    float s = 0.f, s2 = 0.f;
    for (int b = 0; b < BN_; b++) {
        const float* base = outb + ((size_t)b * CHO_ + o) * HW_;
        for (int p = t; p < HW_; p += 256) {
            float v = base[p];
            s += v; s2 += v * v;
        }
    }
#pragma unroll
    for (int off = 32; off > 0; off >>= 1) {
        s  += __shfl_down(s,  off, 64);
        s2 += __shfl_down(s2, off, 64);
    }
    __shared__ float rs[4], rs2[4];
    int lane = t & 63, wv = t >> 6;
    if (lane == 0) { rs[wv] = s; rs2[wv] = s2; }
    __syncthreads();
    if (t == 0) {
        stats[o]        = rs[0] + rs[1] + rs[2] + rs[3];
        stats[CHO_ + o] = rs2[0] + rs2[1] + rs2[2] + rs2[3];
    }
}

// ---------------------------------------------------------------------------
// Kernel 4: BN apply + ReLU, f32 out
// ---------------------------------------------------------------------------
__global__ __launch_bounds__(256) void bn_apply(
    const float* __restrict__ outb, const float* __restrict__ stats,
    const float* __restrict__ gamma, const float* __restrict__ beta,
    float* __restrict__ y)
{
    int idx = blockIdx.x * 256 + threadIdx.x;
    size_t i0 = (size_t)idx * 4;                  // < 9437184
    int o = (int)((i0 / HW_) % CHO_);
    float4 v = *reinterpret_cast<const float4*>(outb + i0);
    const float invN = 1.f / (float)NRED_;
    float mu  = stats[o] * invN;
    float var = stats[CHO_ + o] * invN - mu * mu;
    float inv = rsqrtf(var + BN_EPS_);
    float sc = gamma[o] * inv;
    float sh = beta[o] - mu * sc;
    float4 r;
    r.x = fmaxf(v.x * sc + sh, 0.f);
    r.y = fmaxf(v.y * sc + sh, 0.f);
    r.z = fmaxf(v.z * sc + sh, 0.f);
    r.w = fmaxf(v.w * sc + sh, 0.f);
    *reinterpret_cast<float4*>(y + i0) = r;
}

// ---------------------------------------------------------------------------
extern "C" void kernel_launch(void* const* d_in, const int* in_sizes, int n_in,
                              void* d_out, int out_size, void* d_ws, size_t ws_size,
                              hipStream_t stream)
{
    const float* x   = (const float*)d_in[0];
    const float* wof = (const float*)d_in[1];
    const float* bof = (const float*)d_in[2];
    const float* wcv = (const float*)d_in[3];
    const float* bcv = (const float*)d_in[4];
    const float* gam = (const float*)d_in[5];
    const float* bet = (const float*)d_in[6];
    float* y = (float*)d_out;

    char* ws = (char*)d_ws;
    float*          om    = (float*)ws;                                   // 3.98 MB
    float*          outb  = (float*)(ws + (size_t)4 * 1024 * 1024);       // 36 MB
    float*          stats = (float*)(ws + (size_t)40 * 1024 * 1024);      // 2 KB
    unsigned short* wbf   = (unsigned short*)(ws + (size_t)40 * 1024 * 1024 + 8192);            // 1.125 MB
    unsigned short* wob   = (unsigned short*)(ws + (size_t)40 * 1024 * 1024 + 8192 + 1179648);  // 121.5 KB

    w2b<<<(CHO_ * CK_) / 256, 256, 0, stream>>>(wcv, wbf);        // 2304 blocks
    w2b<<<(27 * CK_) / 256, 256, 0, stream>>>(wof, wob);          // 243 blocks
    offset_mfma<<<BN_ * (HW_ / TPX_), 256, 0, stream>>>(x, wob, bof, om);
    deform_main<<<BN_ * (HW_ / TPX_), 256, 0, stream>>>(x, om, wbf, bcv, outb);
    bn_stats<<<CHO_, 256, 0, stream>>>(outb, stats);
    bn_apply<<<(BN_ * CHO_ * HW_) / (4 * 256), 256, 0, stream>>>(outb, stats, gam, bet, y);
}

// Round 3
// 549.316 us; speedup vs baseline: 1.3186x; 1.3186x over previous
//
#include <hip/hip_runtime.h>
#include <math.h>

// Problem constants (DeformConv_68109591380935) — ALL TENSORS FLOAT32
#define BN_    4
#define CHI_   256
#define CHO_   256
#define HH_    96
#define WW_    96
#define HW_    (HH_*WW_)        // 9216
#define KK_    9
#define CK_    (CHI_*KK_)       // 2304
#define NRED_  (BN_*HW_)        // 36864 samples per BN channel
#define BN_EPS_ 1e-5f

// deform_main tiling: 256 oc x 32 px per block, 1152 blocks (4 blocks/CU).
// s_w / s_cols: pitch 64 shorts (128B rows) + XOR swizzle ((row&7)<<4) —
// bank-conflict-free b128 reads, 40320 B LDS total -> 4 blocks/CU.
#define TPX_   32
#define KC_    64               // K-chunk in LDS

// offset_mfma tiling: 32 oc (27 + 5 zero) x 64 px, KC 96 (UNCHANGED)
#define OTPX_   64
#define OKC_    96
#define OPITCH_ 104             // 208B rows (known-good class)

typedef short short8 __attribute__((ext_vector_type(8)));
typedef float f32x4  __attribute__((ext_vector_type(4)));

// round-to-nearest-even f32 -> bf16 bit pattern
__device__ __forceinline__ unsigned short f2bf(float v) {
    union { float f; unsigned u; } c; c.f = v;
    unsigned lsb = (c.u >> 16) & 1u;
    c.u += 0x7fffu + lsb;
    return (unsigned short)(c.u >> 16);
}

// ---------------------------------------------------------------------------
// Kernel 0: f32 -> bf16 convert (used for w_conv and w_offset)
// ---------------------------------------------------------------------------
__global__ __launch_bounds__(256) void w2b(
    const float* __restrict__ w, unsigned short* __restrict__ wb)
{
    int idx = blockIdx.x * 256 + threadIdx.x;
    wb[idx] = f2bf(w[idx]);
}

// ---------------------------------------------------------------------------
// Kernel 1: offset conv as MFMA GEMM (UNCHANGED from known-good baseline).
//   om[b, 27, HW] = Woff[27,2304] x im2col3x3(x)  + b_offset
// ---------------------------------------------------------------------------
__global__ __launch_bounds__(256) void offset_mfma(
    const float* __restrict__ x, const unsigned short* __restrict__ wob,
    const float* __restrict__ bo, float* __restrict__ om)
{
    __shared__ __align__(16) unsigned short s_w[32 * OPITCH_];     //  6656 B
    __shared__ __align__(16) unsigned short s_cols[OTPX_ * OPITCH_];// 13312 B

    const int t = threadIdx.x;
    const int pixtile = blockIdx.x % (HW_ / OTPX_);  // 144
    const int b       = blockIdx.x / (HW_ / OTPX_);  // 4
    const int p0 = pixtile * OTPX_;

    const int lane = t & 63, wave = t >> 6;
    const int quad = lane >> 4, l15 = lane & 15;

    const int i   = t & 63;            // pixel within tile (staging role)
    const int jlb = (t >> 6) * 24;     // k-subrange within chunk
    const int p   = p0 + i;
    const int h   = p / WW_, w = p % WW_;
    const float* xb = x + (size_t)b * CHI_ * HW_;

    f32x4 acc[2];
    acc[0] = (f32x4){0.f,0.f,0.f,0.f};
    acc[1] = (f32x4){0.f,0.f,0.f,0.f};

    for (int kc = 0; kc < CK_ / OKC_; kc++) {        // 24 chunks
        const int j0 = kc * OKC_;
        if (kc) __syncthreads();
        // ---- stage Woff chunk: 32 x 96 (rows >=27 zero), 3 uint2 per thread
#pragma unroll
        for (int n = 0; n < 3; n++) {
            int e = t + n * 256;                     // < 768
            int ocl = e / 24, kq = e % 24;
            uint2 v = make_uint2(0u, 0u);
            if (ocl < 27)
                v = *reinterpret_cast<const uint2*>(wob + (size_t)ocl * CK_ + j0 + kq * 4);
            *reinterpret_cast<uint2*>(&s_w[ocl * OPITCH_ + kq * 4]) = v;
        }
        // ---- stage im2col chunk: 96 k x 64 px, 24 per thread, 3x b128 write
        union { unsigned short s[24]; uint4 q[3]; } pk;
#pragma unroll
        for (int m = 0; m < 24; m++) {
            int jg = j0 + jlb + m;
            int c  = (jg * 7282) >> 16;              // jg/9
            int k  = jg - 9 * c;
            int yy = h + k / 3 - 1, xx = w + k % 3 - 1;
            bool ok = ((unsigned)yy < HH_) & ((unsigned)xx < WW_);
            float v = ok ? xb[(size_t)c * HW_ + yy * WW_ + xx] : 0.f;
            pk.s[m] = f2bf(v);
        }
        {
            uint4* dst = reinterpret_cast<uint4*>(&s_cols[i * OPITCH_ + jlb]);
            dst[0] = pk.q[0]; dst[1] = pk.q[1]; dst[2] = pk.q[2];
        }
        __syncthreads();
        // ---- MFMA: 3 K-steps, A = 2 oc-tiles, B = this wave's pixel quarter
#pragma unroll
        for (int ks = 0; ks < OKC_ / 32; ks++) {
            short8 a0 = *reinterpret_cast<const short8*>(
                &s_w[(l15) * OPITCH_ + ks * 32 + quad * 8]);
            short8 a1 = *reinterpret_cast<const short8*>(
                &s_w[(16 + l15) * OPITCH_ + ks * 32 + quad * 8]);
            short8 b0 = *reinterpret_cast<const short8*>(
                &s_cols[(wave * 16 + l15) * OPITCH_ + ks * 32 + quad * 8]);
            acc[0] = __builtin_amdgcn_mfma_f32_16x16x32_bf16(a0, b0, acc[0], 0, 0, 0);
            acc[1] = __builtin_amdgcn_mfma_f32_16x16x32_bf16(a1, b0, acc[1], 0, 0, 0);
        }
    }

    // epilogue: C/D layout col=lane&15 (pixel), row=quad*4+r (oc)
#pragma unroll
    for (int mt = 0; mt < 2; mt++) {
#pragma unroll
        for (int r = 0; r < 4; r++) {
            int oc = mt * 16 + quad * 4 + r;
            if (oc < 27) {
                int pix = p0 + wave * 16 + l15;
                om[((size_t)b * 27 + oc) * HW_ + pix] = acc[mt][r] + bo[oc];
            }
        }
    }
}

// ---------------------------------------------------------------------------
// Kernel 2: fused deformable gather + bf16 MFMA GEMM
//   R3: 256 oc x 32 px blocks (1152 total), 4 blocks/CU via 40320B LDS;
//       gather math IDENTICAL to known-good R0; XOR-swizzled s_w/s_cols;
//       XCD-aware contiguous-tile remap. acc 4x2 per wave.
// ---------------------------------------------------------------------------
__global__ __launch_bounds__(256, 4) void deform_main(
    const float* __restrict__ x, const float* __restrict__ om,
    const unsigned short* __restrict__ wb, const float* __restrict__ bconv,
    float* __restrict__ outb)
{
    __shared__ __align__(16) unsigned short s_w[CHO_ * 64];      // 32768 B (swizzled)
    __shared__ __align__(16) unsigned short s_cols[TPX_ * 64];   //  4096 B (swizzled)
    __shared__ float s_py[KK_ * TPX_], s_px[KK_ * TPX_], s_mask[KK_ * TPX_]; // 3456 B

    const int t = threadIdx.x;
    // XCD-aware bijective remap: 1152 blocks = 8 XCDs x 144 contiguous tiles.
    // Dispatcher round-robins bid across XCDs -> give each XCD a contiguous
    // half-image of tiles so its 4MB L2 holds the per-chunk x working set.
    const int bid = blockIdx.x;
    const int j   = (bid & 7) * 144 + (bid >> 3);    // [0,1152)
    const int pixtile = j % (HW_ / TPX_);            // 288
    const int b       = j / (HW_ / TPX_);            // 4
    const int p0 = pixtile * TPX_;

    // ---- meta: py/px/mask for 9 taps x 32 pixels (R0 form) ----
    for (int e = t; e < KK_ * TPX_; e += 256) {
        int k = e >> 5, i = e & 31;                  // TPX_ == 32
        int p = p0 + i;
        int h = p / WW_, w = p % WW_;
        const float* omb = om + ((size_t)b * 27) * HW_ + p;
        float dy = omb[(2 * k) * HW_];
        float dx = omb[(2 * k + 1) * HW_];
        float m  = omb[(18 + k) * HW_];
        s_py[e]   = dy + (float)(h + k / 3 - 1);
        s_px[e]   = dx + (float)(w + (k % 3) - 1);
        s_mask[e] = 1.f / (1.f + __expf(-m));
    }

    const int lane = t & 63, wave = t >> 6;
    const int quad = lane >> 4, l15 = lane & 15;
    const int ib   = t & 31;           // pixel (staging role)
    const int jq   = t >> 5;           // k-group 0..7 (8 k each)
    const int jlb  = jq << 3;

    f32x4 acc[4][2];
#pragma unroll
    for (int m = 0; m < 4; m++)
#pragma unroll
        for (int n = 0; n < 2; n++)
            acc[m][n] = (f32x4){0.f, 0.f, 0.f, 0.f};

    const float* xb = x + (size_t)b * CHI_ * HW_;
    char* swb = (char*)s_w;
    char* scb = (char*)s_cols;

    __syncthreads();   // meta visible

    for (int kc = 0; kc < CK_ / KC_; kc++) {       // 36 chunks
        const int j0 = kc * KC_;
        if (kc) __syncthreads();
        // ---- stage W chunk: 256 oc x 64 k, 8 x uint4 per thread, swizzled
#pragma unroll
        for (int n = 0; n < 8; n++) {
            int e = t + n * 256;                   // < 2048
            int ocl = e >> 3, ko = e & 7;
            uint4 v = *reinterpret_cast<const uint4*>(
                wb + (size_t)ocl * CK_ + j0 + ko * 8);
            int boff = (ocl << 7) + ((ko << 4) ^ ((ocl & 7) << 4));
            *reinterpret_cast<uint4*>(swb + boff) = v;
        }
        // ---- stage cols: 64 k x 32 px bilinear gather, 8/thread (R0 math)
        union { unsigned short s[8]; uint4 q; } pk;
#pragma unroll
        for (int m = 0; m < 8; m++) {
            int jg = j0 + jlb + m;
            int c  = (jg * 7282) >> 16;           // jg/9
            int k  = jg - 9 * c;
            float py = s_py[k * TPX_ + ib], px = s_px[k * TPX_ + ib];
            float y0f = floorf(py), x0f = floorf(px);
            float ly = py - y0f, lx = px - x0f;
            int y0 = (int)y0f, x0 = (int)x0f;
            float vy0 = ((unsigned)y0       < HH_) ? 1.f : 0.f;
            float vy1 = ((unsigned)(y0 + 1) < HH_) ? 1.f : 0.f;
            float vx0 = ((unsigned)x0       < WW_) ? 1.f : 0.f;
            float vx1 = ((unsigned)(x0 + 1) < WW_) ? 1.f : 0.f;
            int yc0 = min(max(y0, 0), HH_ - 1), yc1 = min(max(y0 + 1, 0), HH_ - 1);
            int xc0 = min(max(x0, 0), WW_ - 1), xc1 = min(max(x0 + 1, 0), WW_ - 1);
            const float* img = xb + (size_t)c * HW_;
            float f00 = img[yc0 * WW_ + xc0];
            float f01 = img[yc0 * WW_ + xc1];
            float f10 = img[yc1 * WW_ + xc0];
            float f11 = img[yc1 * WW_ + xc1];
            float wy0 = 1.f - ly, wx0 = 1.f - lx;
            float v = f00 * (wy0 * wx0 * vy0 * vx0) + f01 * (wy0 * lx * vy0 * vx1)
                    + f10 * (ly  * wx0 * vy1 * vx0) + f11 * (ly  * lx * vy1 * vx1);
            pk.s[m] = f2bf(v * s_mask[k * TPX_ + ib]);
        }
        {
            int boff = (ib << 7) + ((jq << 4) ^ ((ib & 7) << 4));
            *reinterpret_cast<uint4*>(scb + boff) = pk.q;
        }
        __syncthreads();
        // ---- MFMA: 2 K-steps of 32; wave = 64-oc slice, 32 px ----
#pragma unroll
        for (int ks = 0; ks < KC_ / 32; ks++) {
            short8 afr[4], bfr[2];
#pragma unroll
            for (int m = 0; m < 4; m++) {
                int row  = wave * 64 + m * 16 + l15;
                int boff = (row << 7) + (((ks << 6) + (quad << 4)) ^ ((row & 7) << 4));
                afr[m] = *reinterpret_cast<const short8*>(swb + boff);
            }
#pragma unroll
            for (int n = 0; n < 2; n++) {
                int row  = n * 16 + l15;
                int boff = (row << 7) + (((ks << 6) + (quad << 4)) ^ ((row & 7) << 4));
                bfr[n] = *reinterpret_cast<const short8*>(scb + boff);
            }
#pragma unroll
            for (int m = 0; m < 4; m++)
#pragma unroll
                for (int n = 0; n < 2; n++)
                    acc[m][n] = __builtin_amdgcn_mfma_f32_16x16x32_bf16(
                        afr[m], bfr[n], acc[m][n], 0, 0, 0);
        }
    }

    // ---- epilogue: C/D layout col=lane&15 (pixel), row=quad*4+r (oc) ----
#pragma unroll
    for (int m = 0; m < 4; m++) {
#pragma unroll
        for (int n = 0; n < 2; n++) {
#pragma unroll
            for (int r = 0; r < 4; r++) {
                int oc  = wave * 64 + m * 16 + quad * 4 + r;
                int pix = p0 + n * 16 + l15;
                outb[((size_t)b * CHO_ + oc) * HW_ + pix] = acc[m][n][r] + bconv[oc];
            }
        }
    }
}

// ---------------------------------------------------------------------------
// Kernel 3: BN statistics (sum, sumsq) per channel, deterministic two-pass
// ---------------------------------------------------------------------------
__global__ __launch_bounds__(256) void bn_stats(
    const float* __restrict__ outb, float* __restrict__ stats)
{
    int o = blockIdx.x, t = threadIdx.x;
    float s = 0.f, s2 = 0.f;
    for (int b = 0; b < BN_; b++) {
        const float* base = outb + ((size_t)b * CHO_ + o) * HW_;
        for (int p = t; p < HW_; p += 256) {
            float v = base[p];
            s += v; s2 += v * v;
        }
    }
#pragma unroll
    for (int off = 32; off > 0; off >>= 1) {
        s  += __shfl_down(s,  off, 64);
        s2 += __shfl_down(s2, off, 64);
    }
    __shared__ float rs[4], rs2[4];
    int lane = t & 63, wv = t >> 6;
    if (lane == 0) { rs[wv] = s; rs2[wv] = s2; }
    __syncthreads();
    if (t == 0) {
        stats[o]        = rs[0] + rs[1] + rs[2] + rs[3];
        stats[CHO_ + o] = rs2[0] + rs2[1] + rs2[2] + rs2[3];
    }
}

// ---------------------------------------------------------------------------
// Kernel 4: BN apply + ReLU, f32 out
// ---------------------------------------------------------------------------
__global__ __launch_bounds__(256) void bn_apply(
    const float* __restrict__ outb, const float* __restrict__ stats,
    const float* __restrict__ gamma, const float* __restrict__ beta,
    float* __restrict__ y)
{
    int idx = blockIdx.x * 256 + threadIdx.x;
    size_t i0 = (size_t)idx * 4;                  // < 9437184
    int o = (int)((i0 / HW_) % CHO_);
    float4 v = *reinterpret_cast<const float4*>(outb + i0);
    const float invN = 1.f / (float)NRED_;
    float mu  = stats[o] * invN;
    float var = stats[CHO_ + o] * invN - mu * mu;
    float inv = rsqrtf(var + BN_EPS_);
    float sc = gamma[o] * inv;
    float sh = beta[o] - mu * sc;
    float4 r;
    r.x = fmaxf(v.x * sc + sh, 0.f);
    r.y = fmaxf(v.y * sc + sh, 0.f);
    r.z = fmaxf(v.z * sc + sh, 0.f);
    r.w = fmaxf(v.w * sc + sh, 0.f);
    *reinterpret_cast<float4*>(y + i0) = r;
}

// ---------------------------------------------------------------------------
extern "C" void kernel_launch(void* const* d_in, const int* in_sizes, int n_in,
                              void* d_out, int out_size, void* d_ws, size_t ws_size,
                              hipStream_t stream)
{
    const float* x   = (const float*)d_in[0];
    const float* wof = (const float*)d_in[1];
    const float* bof = (const float*)d_in[2];
    const float* wcv = (const float*)d_in[3];
    const float* bcv = (const float*)d_in[4];
    const float* gam = (const float*)d_in[5];
    const float* bet = (const float*)d_in[6];
    float* y = (float*)d_out;

    char* ws = (char*)d_ws;
    float*          om    = (float*)ws;                                   // 3.98 MB
    float*          outb  = (float*)(ws + (size_t)4 * 1024 * 1024);       // 36 MB
    float*          stats = (float*)(ws + (size_t)40 * 1024 * 1024);      // 2 KB
    unsigned short* wbf   = (unsigned short*)(ws + (size_t)40 * 1024 * 1024 + 8192);            // 1.125 MB
    unsigned short* wob   = (unsigned short*)(ws + (size_t)40 * 1024 * 1024 + 8192 + 1179648);  // 121.5 KB

    w2b<<<(CHO_ * CK_) / 256, 256, 0, stream>>>(wcv, wbf);        // 2304 blocks
    w2b<<<(27 * CK_) / 256, 256, 0, stream>>>(wof, wob);          // 243 blocks
    offset_mfma<<<BN_ * (HW_ / OTPX_), 256, 0, stream>>>(x, wob, bof, om);
    deform_main<<<BN_ * (HW_ / TPX_), 256, 0, stream>>>(x, om, wbf, bcv, outb);
    bn_stats<<<CHO_, 256, 0, stream>>>(outb, stats);
    bn_apply<<<(BN_ * CHO_ * HW_) / (4 * 256), 256, 0, stream>>>(outb, stats, gam, bet, y);
}